// Round 10
// baseline (14790.416 us; speedup 1.0000x reference)
//
#include <hip/hip_runtime.h>
#include <math.h>

namespace {

typedef __attribute__((ext_vector_type(8))) _Float16 h8v;  // 8 x fp16 = one MFMA frag
typedef __attribute__((ext_vector_type(4))) float f4;
typedef unsigned long long u64;

constexpr int B_ = 128;
constexpr int T_ = 500;
constexpr int F_ = 64;
constexpr int U_ = 512;
constexpr int NCLS_ = 11;
constexpr float R_ON_ = 0.05f;
constexpr float ALPHA_ = 0.001f;
constexpr float LO_SCALE = 1.0f / 2048.0f;

constexpr int TEAMS = 8;              // 16 batch rows each -- fully independent
constexpr int SLICES = 32;            // 16 units (of each cell) per slice-block
constexpr int NBLK = TEAMS * SLICES;  // 256; bid = team*32 + s  ->  XCD = s % 8
constexpr int NPH = 502;
constexpr int WFRAGS = 400;           // per slice: 144 (cell0) + 256 (cell1)
constexpr int WSLICE = WFRAGS * 512;  // ushorts per slice (400 KB)
constexpr int SSTRIDE = U_ * 16;      // 8192 ushorts per state buffer

union hu16 { ushort u; _Float16 h; };
__device__ __forceinline__ ushort f2h(float f) { hu16 v; v.h = (_Float16)f; return v.u; }

__device__ __forceinline__ u64 ld_a64(const ushort* p) {
  return __hip_atomic_load((const u64*)p, __ATOMIC_RELAXED, __HIP_MEMORY_SCOPE_AGENT);
}
__device__ __forceinline__ void st_a64(ushort* p, u64 v) {
  __hip_atomic_store((u64*)p, v, __ATOMIC_RELAXED, __HIP_MEMORY_SCOPE_AGENT);
}
// 16B LLC-coherent state-fragment load via two compiler-tracked atomic loads
__device__ __forceinline__ h8v ldA(const ushort* p) {
  union { u64 q[2]; h8v v; } r;
  r.q[0] = ld_a64(p);
  r.q[1] = ld_a64(p + 4);
  return r.v;
}
__device__ __forceinline__ u64 pack4(const ushort* h) {
  return (u64)h[0] | ((u64)h[1] << 16) | ((u64)h[2] << 32) | ((u64)h[3] << 48);
}
// state frag byte-order: elem (r, k) at ((k>>5)*64 + (r | (((k>>3)&3)<<4)))*8 + (k&7)
__device__ __forceinline__ int faddr(int r, int k) {
  return ((k >> 5) * 64 + (r | (((k >> 3) & 3) << 4))) * 8 + (k & 7);
}

// One-time: pack dual-fp16 weights into MFMA-frag order, zero state, transpose
// times, zero barrier.
__global__ void init_kernel(ushort* wp, unsigned* st_u32, float* timesT, unsigned* bar,
                            const float* k0, const float* rk0,
                            const float* k1, const float* rk1,
                            const float* times)
{
  const long long gid = (long long)blockIdx.x * blockDim.x + threadIdx.x;
  const long long stride = (long long)gridDim.x * blockDim.x;
  for (long long i = gid; i < (long long)SLICES * WSLICE; i += stride) {
    const int s = (int)(i / WSLICE);
    const int rem = (int)(i % WSLICE);
    const int f = rem >> 9;
    const int e = rem & 511;
    const int lane = e >> 3, j = e & 7;
    const bool c1 = f >= 144;
    const int fl = c1 ? f - 144 : f;
    const int ch = fl >> 3, ct = (fl >> 1) & 3, hl = fl & 1;
    const int c = ct * 16 + (lane & 15);
    const int n = (c & 3) * 512 + s * 16 + (c >> 2);
    const int kk = ch * 32 + (lane >> 4) * 8 + j;
    float w;
    if (!c1) w = (kk < 64)  ? k0[(size_t)kk * 2048 + n] : rk0[(size_t)(kk - 64) * 2048 + n];
    else     w = (kk < 512) ? k1[(size_t)kk * 2048 + n] : rk1[(size_t)(kk - 512) * 2048 + n];
    const _Float16 hi = (_Float16)w;
    hu16 o;
    o.h = hl ? (_Float16)((w - (float)hi) * 2048.0f) : hi;
    wp[i] = o.u;
  }
  for (long long i = gid; i < 131072; i += stride) st_u32[i] = 0u;  // 32*8192 ushorts
  for (long long i = gid; i < (long long)T_ * B_; i += stride) {
    const int t = (int)(i >> 7), b = (int)(i & 127);
    timesT[i] = times[(size_t)b * T_ + t];
  }
  for (long long i = gid; i < 8192; i += stride) bar[i] = 0u;
}

// 256 blocks x 64 threads (1 wave). Block (team, s): 16 batch rows, 16 units
// of cell0 AND cell1. Phase p: cell0 t=p, cell1 t=p-1, cls t=p-2.
// Sync: per-TEAM flag barrier (32 blocks), no device-wide coupling.
__global__ __launch_bounds__(64, 1) void plstm_kernel(
    const float* __restrict__ inputs,
    const float* __restrict__ b0v, const float* __restrict__ tau0, const float* __restrict__ s0v,
    const float* __restrict__ b1v, const float* __restrict__ tau1, const float* __restrict__ s1v,
    const float* __restrict__ wfc, const float* __restrict__ bfc,
    float* __restrict__ out,
    const ushort* __restrict__ wp, ushort* __restrict__ st,
    const float* __restrict__ timesT, unsigned* __restrict__ bar)
{
  __shared__ float z0[64 * 17];
  __shared__ float z1[64 * 17];

  const int bid = blockIdx.x;
  const int team = bid >> 5, s = bid & 31;
  const int lane = threadIdx.x;
  const int rlo = lane & 15, khi = lane >> 4;
  const int rbase = khi * 4;
  const ushort* wps = wp + (size_t)s * WSLICE;
  const int brow = team * 16 + rlo;        // this lane's batch row (gemm view)
  const int u0g = s * 16 + khi * 4;        // this lane's first unit (elem view)

  float cc0[4] = {0.f, 0.f, 0.f, 0.f}, hh0[4] = {0.f, 0.f, 0.f, 0.f};
  float cc1[4] = {0.f, 0.f, 0.f, 0.f}, hh1[4] = {0.f, 0.f, 0.f, 0.f};

  for (unsigned p = 0; p < NPH; ++p) {
    const ushort* h0r = st + (size_t)(team * 2 + (p & 1)) * SSTRIDE;
    ushort* h0w       = st + (size_t)(team * 2 + ((p + 1) & 1)) * SSTRIDE;
    const ushort* h1r = st + (size_t)(16 + team * 2 + (p & 1)) * SSTRIDE;
    ushort* h1w       = st + (size_t)(16 + team * 2 + ((p + 1) & 1)) * SSTRIDE;
    const bool w0 = (p < T_);
    const int t1 = (int)p - 1;
    const bool w1 = (t1 >= 0 && t1 < T_);
    const int tc = (int)p - 2;
    const bool wc = (tc >= 0 && tc < T_);

    if (w0) {
      // ---- cell0 GEMM: K = 576 (2 x-chunks + 16 h0-chunks) ----
      h8v xf0, xf1;
      {
        const float* xp = inputs + ((size_t)brow * T_ + p) * F_ + khi * 8;
        const f4 a = *(const f4*)xp, b = *(const f4*)(xp + 4);
        const f4 c = *(const f4*)(xp + 32), d = *(const f4*)(xp + 36);
#pragma unroll
        for (int j = 0; j < 4; ++j) {
          xf0[j] = (_Float16)a[j]; xf0[4 + j] = (_Float16)b[j];
          xf1[j] = (_Float16)c[j]; xf1[4 + j] = (_Float16)d[j];
        }
      }
      f4 A0[4] = {}, A1[4] = {};
#pragma unroll 6
      for (int ch = 0; ch < 18; ++ch) {
        const h8v af = (ch == 0) ? xf0 : (ch == 1) ? xf1
                      : ldA(h0r + ((ch - 2) * 64 + lane) * 8);
#pragma unroll
        for (int ct = 0; ct < 4; ++ct) {
          const h8v whi = *(const h8v*)(wps + ((size_t)((ch * 4 + ct) * 2 + 0)) * 512 + lane * 8);
          const h8v wlo = *(const h8v*)(wps + ((size_t)((ch * 4 + ct) * 2 + 1)) * 512 + lane * 8);
          A0[ct] = __builtin_amdgcn_mfma_f32_16x16x32_f16(af, whi, A0[ct], 0, 0, 0);
          A1[ct] = __builtin_amdgcn_mfma_f32_16x16x32_f16(af, wlo, A1[ct], 0, 0, 0);
        }
      }
#pragma unroll
      for (int ct = 0; ct < 4; ++ct) {
        const f4 red = A0[ct] + A1[ct] * LO_SCALE;
#pragma unroll
        for (int j = 0; j < 4; ++j)
          z0[(ct * 16 + rlo) * 17 + rbase + j] = red[j];
      }
    }

    if (w1) {
      // ---- cell1 GEMM: K = 1024 (16 h0(t1)-chunks + 16 h1(t1-1)-chunks) ----
      f4 A0[4] = {}, A1[4] = {};
#pragma unroll 8
      for (int ch = 0; ch < 32; ++ch) {
        const ushort* Ab = (ch < 16) ? h0r : h1r;
        const int cs = ch & 15;
        const h8v af = ldA(Ab + (cs * 64 + lane) * 8);
#pragma unroll
        for (int ct = 0; ct < 4; ++ct) {
          const h8v whi = *(const h8v*)(wps + ((size_t)(144 + (ch * 4 + ct) * 2 + 0)) * 512 + lane * 8);
          const h8v wlo = *(const h8v*)(wps + ((size_t)(144 + (ch * 4 + ct) * 2 + 1)) * 512 + lane * 8);
          A0[ct] = __builtin_amdgcn_mfma_f32_16x16x32_f16(af, whi, A0[ct], 0, 0, 0);
          A1[ct] = __builtin_amdgcn_mfma_f32_16x16x32_f16(af, wlo, A1[ct], 0, 0, 0);
        }
      }
#pragma unroll
      for (int ct = 0; ct < 4; ++ct) {
        const f4 red = A0[ct] + A1[ct] * LO_SCALE;
#pragma unroll
        for (int j = 0; j < 4; ++j)
          z1[(ct * 16 + rlo) * 17 + rbase + j] = red[j];
      }
    }
    __syncthreads();

    // ---- elementwise PhasedLSTM updates (lane = row rlo, units u0g..+3) ----
    if (w0) {
      const float tt = timesT[p * B_ + brow];
      ushort vh[4];
#pragma unroll
      for (int i = 0; i < 4; ++i) {
        const int ul = khi * 4 + i, u = u0g + i;
        const float zi = z0[(ul * 4 + 0) * 17 + rlo] + b0v[u];
        const float zf = z0[(ul * 4 + 1) * 17 + rlo] + b0v[512 + u];
        const float zg = z0[(ul * 4 + 2) * 17 + rlo] + b0v[1024 + u];
        const float zo = z0[(ul * 4 + 3) * 17 + rlo] + b0v[1536 + u];
        const float ig = 1.f / (1.f + expf(-zi));
        const float fg = 1.f / (1.f + expf(-zf));
        const float gg = tanhf(zg);
        const float og = 1.f / (1.f + expf(-zo));
        const float c_t = fg * cc0[i] + ig * gg;
        const float h_t = og * tanhf(c_t);
        const float tau_u = tau0[u];
        float phi = fmodf(tt - s0v[u], tau_u);
        if (phi < 0.f) phi += tau_u;
        phi /= tau_u;
        float kt;
        if (phi < 0.5f * R_ON_) kt = phi * (2.0f / R_ON_);
        else if (phi < R_ON_)   kt = 2.0f - phi * (2.0f / R_ON_);
        else                    kt = ALPHA_ * phi;
        cc0[i] = kt * c_t + (1.0f - kt) * cc0[i];
        hh0[i] = kt * h_t + (1.0f - kt) * hh0[i];
        vh[i] = f2h(hh0[i]);
      }
      st_a64(h0w + faddr(rlo, u0g), pack4(vh));
    }
    if (w1) {
      const float tt = timesT[t1 * B_ + brow];
      ushort vh[4];
#pragma unroll
      for (int i = 0; i < 4; ++i) {
        const int ul = khi * 4 + i, u = u0g + i;
        const float zi = z1[(ul * 4 + 0) * 17 + rlo] + b1v[u];
        const float zf = z1[(ul * 4 + 1) * 17 + rlo] + b1v[512 + u];
        const float zg = z1[(ul * 4 + 2) * 17 + rlo] + b1v[1024 + u];
        const float zo = z1[(ul * 4 + 3) * 17 + rlo] + b1v[1536 + u];
        const float ig = 1.f / (1.f + expf(-zi));
        const float fg = 1.f / (1.f + expf(-zf));
        const float gg = tanhf(zg);
        const float og = 1.f / (1.f + expf(-zo));
        const float c_t = fg * cc1[i] + ig * gg;
        const float h_t = og * tanhf(c_t);
        const float tau_u = tau1[u];
        float phi = fmodf(tt - s1v[u], tau_u);
        if (phi < 0.f) phi += tau_u;
        phi /= tau_u;
        float kt;
        if (phi < 0.5f * R_ON_) kt = phi * (2.0f / R_ON_);
        else if (phi < R_ON_)   kt = 2.0f - phi * (2.0f / R_ON_);
        else                    kt = ALPHA_ * phi;
        cc1[i] = kt * c_t + (1.0f - kt) * cc1[i];
        hh1[i] = kt * h_t + (1.0f - kt) * hh1[i];
        vh[i] = f2h(hh1[i]);
      }
      st_a64(h1w + faddr(rlo, u0g), pack4(vh));
    }

    // ---- classifier: blocks s<16, row = team*16+s, t = p-2 ----
    if (wc && s < 16) {
      const int u = lane * 8;
      const int e = ((lane >> 2) * 64 + (s | ((lane & 3) << 4))) * 8;
      const u64 d0 = ld_a64(h1r + e);
      const u64 d1 = ld_a64(h1r + e + 4);
      float acc[NCLS_];
#pragma unroll
      for (int c = 0; c < NCLS_; ++c) acc[c] = 0.f;
#pragma unroll
      for (int j = 0; j < 8; ++j) {
        hu16 hb; hb.u = (ushort)(((j < 4) ? d0 : d1) >> (16 * (j & 3)));
        const float h = (float)hb.h;
        const float* wr = wfc + (size_t)(u + j) * NCLS_;
#pragma unroll
        for (int c = 0; c < NCLS_; ++c) acc[c] = fmaf(h, wr[c], acc[c]);
      }
#pragma unroll
      for (int off = 32; off >= 1; off >>= 1) {
#pragma unroll
        for (int c = 0; c < NCLS_; ++c) acc[c] += __shfl_xor(acc[c], off, 64);
      }
      if (lane == 0) {
        float lg[NCLS_];
        float m = -1e30f;
#pragma unroll
        for (int c = 0; c < NCLS_; ++c) { lg[c] = acc[c] + bfc[c]; m = fmaxf(m, lg[c]); }
        float sm = 0.f;
#pragma unroll
        for (int c = 0; c < NCLS_; ++c) { lg[c] = expf(lg[c] - m); sm += lg[c]; }
        const float inv = 1.0f / sm;
        float* op = out + ((size_t)(team * 16 + s) * T_ + tc) * NCLS_;
#pragma unroll
        for (int c = 0; c < NCLS_; ++c) op[c] = lg[c] * inv;
      }
    }

    // ---- per-TEAM barrier (32 blocks), RMW-free, monotonic flags ----
    if (p < NPH - 1) {
      asm volatile("s_waitcnt vmcnt(0)" ::: "memory");  // drain state stores
      if (lane == 0)
        __hip_atomic_store(&bar[bid * 16], p + 1u, __ATOMIC_RELAXED, __HIP_MEMORY_SCOPE_AGENT);
      if (s == 0) {
        if (lane < SLICES) {
          while (__hip_atomic_load(&bar[(team * 32 + lane) * 16], __ATOMIC_RELAXED,
                                   __HIP_MEMORY_SCOPE_AGENT) < p + 1u)
            __builtin_amdgcn_s_sleep(2);
        }
        if (lane == 0)
          __hip_atomic_store(&bar[4096 + team * 16], p + 1u, __ATOMIC_RELAXED,
                             __HIP_MEMORY_SCOPE_AGENT);
      } else {
        if (lane == 0) {
          while (__hip_atomic_load(&bar[4096 + team * 16], __ATOMIC_RELAXED,
                                   __HIP_MEMORY_SCOPE_AGENT) < p + 1u)
            __builtin_amdgcn_s_sleep(2);
        }
      }
      asm volatile("" ::: "memory");  // no reordering of memory ops across wake
      __syncthreads();
    }
  }
}

}  // namespace

extern "C" void kernel_launch(void* const* d_in, const int* in_sizes, int n_in,
                              void* d_out, int out_size, void* d_ws, size_t ws_size,
                              hipStream_t stream) {
  const float* inputs = (const float*)d_in[0];
  const float* times  = (const float*)d_in[1];
  const float* k0     = (const float*)d_in[2];
  const float* rk0    = (const float*)d_in[3];
  const float* b0     = (const float*)d_in[4];
  const float* tau0   = (const float*)d_in[5];
  const float* s0     = (const float*)d_in[6];
  const float* k1     = (const float*)d_in[7];
  const float* rk1    = (const float*)d_in[8];
  const float* b1     = (const float*)d_in[9];
  const float* tau1   = (const float*)d_in[10];
  const float* s1     = (const float*)d_in[11];
  const float* wfc    = (const float*)d_in[12];
  const float* bfc    = (const float*)d_in[13];
  float* out = (float*)d_out;

  // ws layout: wp[32*WSLICE ushort] | st[32*8192 ushort] | timesT[T*B f32] | bar[8192 u32]
  ushort* wp = (ushort*)d_ws;
  ushort* st = wp + (size_t)SLICES * WSLICE;
  float* timesT = (float*)(st + 32 * SSTRIDE);
  unsigned* bar = (unsigned*)(timesT + (size_t)T_ * B_);

  hipLaunchKernelGGL(init_kernel, dim3(2048), dim3(256), 0, stream,
                     wp, (unsigned*)st, timesT, bar, k0, rk0, k1, rk1, times);
  hipLaunchKernelGGL(plstm_kernel, dim3(NBLK), dim3(64), 0, stream,
                     inputs, b0, tau0, s0, b1, tau1, s1, wfc, bfc, out,
                     wp, st, timesT, bar);
}

// Round 11
// 13551.317 us; speedup vs baseline: 1.0914x; 1.0914x over previous
//
#include <hip/hip_runtime.h>
#include <math.h>

namespace {

typedef __attribute__((ext_vector_type(8))) _Float16 h8v;  // 8 x fp16 = one MFMA frag
typedef __attribute__((ext_vector_type(4))) float f4;
typedef unsigned long long u64;

constexpr int B_ = 128;
constexpr int T_ = 500;
constexpr int F_ = 64;
constexpr int U_ = 512;
constexpr int NCLS_ = 11;
constexpr float R_ON_ = 0.05f;
constexpr float ALPHA_ = 0.001f;
constexpr float LO_SCALE = 1.0f / 2048.0f;

constexpr int TEAMS = 8;              // 16 batch rows each -- fully independent
constexpr int SLICES = 32;            // 16 units (of each cell) per slice-block
constexpr int NBLK = TEAMS * SLICES;  // 256; bid = team*32 + s
constexpr int NPH = 502;
constexpr int WFRAGS = 400;           // per slice: 144 (cell0) + 256 (cell1)
constexpr int WSLICE = WFRAGS * 512;  // ushorts per slice (400 KB)
constexpr int SSTRIDE = U_ * 16;      // 8192 ushorts per state buffer

union hu16 { ushort u; _Float16 h; };
__device__ __forceinline__ ushort f2h(float f) { hu16 v; v.h = (_Float16)f; return v.u; }

__device__ __forceinline__ u64 ld_a64(const ushort* p) {
  return __hip_atomic_load((const u64*)p, __ATOMIC_RELAXED, __HIP_MEMORY_SCOPE_AGENT);
}
__device__ __forceinline__ void st_a64(ushort* p, u64 v) {
  __hip_atomic_store((u64*)p, v, __ATOMIC_RELAXED, __HIP_MEMORY_SCOPE_AGENT);
}
// 16B LLC-coherent state-fragment load via two compiler-tracked atomic loads
__device__ __forceinline__ h8v ldA(const ushort* p) {
  union { u64 q[2]; h8v v; } r;
  r.q[0] = ld_a64(p);
  r.q[1] = ld_a64(p + 4);
  return r.v;
}
__device__ __forceinline__ u64 pack4(const ushort* h) {
  return (u64)h[0] | ((u64)h[1] << 16) | ((u64)h[2] << 32) | ((u64)h[3] << 48);
}
// state frag order: elem (r, k) at ((k>>5)*64 + (r | (((k>>3)&3)<<4)))*8 + (k&7)
__device__ __forceinline__ int faddr(int r, int k) {
  return ((k >> 5) * 64 + (r | (((k >> 3) & 3) << 4))) * 8 + (k & 7);
}

// One-time: pack dual-fp16 weights into MFMA-frag order, zero state, transpose
// times, zero barrier. (identical to R10)
__global__ void init_kernel(ushort* wp, unsigned* st_u32, float* timesT, unsigned* bar,
                            const float* k0, const float* rk0,
                            const float* k1, const float* rk1,
                            const float* times)
{
  const long long gid = (long long)blockIdx.x * blockDim.x + threadIdx.x;
  const long long stride = (long long)gridDim.x * blockDim.x;
  for (long long i = gid; i < (long long)SLICES * WSLICE; i += stride) {
    const int s = (int)(i / WSLICE);
    const int rem = (int)(i % WSLICE);
    const int f = rem >> 9;
    const int e = rem & 511;
    const int lane = e >> 3, j = e & 7;
    const bool c1 = f >= 144;
    const int fl = c1 ? f - 144 : f;
    const int ch = fl >> 3, ct = (fl >> 1) & 3, hl = fl & 1;
    const int c = ct * 16 + (lane & 15);
    const int n = (c & 3) * 512 + s * 16 + (c >> 2);
    const int kk = ch * 32 + (lane >> 4) * 8 + j;
    float w;
    if (!c1) w = (kk < 64)  ? k0[(size_t)kk * 2048 + n] : rk0[(size_t)(kk - 64) * 2048 + n];
    else     w = (kk < 512) ? k1[(size_t)kk * 2048 + n] : rk1[(size_t)(kk - 512) * 2048 + n];
    const _Float16 hi = (_Float16)w;
    hu16 o;
    o.h = hl ? (_Float16)((w - (float)hi) * 2048.0f) : hi;
    wp[i] = o.u;
  }
  for (long long i = gid; i < 131072; i += stride) st_u32[i] = 0u;  // 32*8192 ushorts
  for (long long i = gid; i < (long long)T_ * B_; i += stride) {
    const int t = (int)(i >> 7), b = (int)(i & 127);
    timesT[i] = times[(size_t)b * T_ + t];
  }
  for (long long i = gid; i < 8192; i += stride) bar[i] = 0u;
}

// 256 blocks x 512 threads (8 waves). Block (team, s): 16 batch rows, 16
// units of cell0 AND cell1. K-chunks split across the 8 waves; z reduced via
// LDS atomicAdd. Phase p: cell0 t=p, cell1 t=p-1, cls t=p-2.
// Sync: per-TEAM flag barrier (32 blocks), no device-wide coupling.
__global__ __launch_bounds__(512, 1) void plstm_kernel(
    const float* __restrict__ inputs,
    const float* __restrict__ b0v, const float* __restrict__ tau0, const float* __restrict__ s0v,
    const float* __restrict__ b1v, const float* __restrict__ tau1, const float* __restrict__ s1v,
    const float* __restrict__ wfc, const float* __restrict__ bfc,
    float* __restrict__ out,
    const ushort* __restrict__ wp, ushort* __restrict__ st,
    const float* __restrict__ timesT, unsigned* __restrict__ bar)
{
  __shared__ float z0[64 * 17];
  __shared__ float z1[64 * 17];

  const int bid = blockIdx.x;
  const int team = bid >> 5, s = bid & 31;
  const int tid = threadIdx.x;
  const int w = tid >> 6;
  const int lane = tid & 63;
  const int rlo = lane & 15, khi = lane >> 4;
  const int rbase = khi * 4;
  const ushort* wps = wp + (size_t)s * WSLICE;
  const int brow = team * 16 + rlo;        // this lane's batch row (gemm view)
  const int u0g = s * 16 + khi * 4;        // this lane's first unit (elem view)

  // K-chunk ranges per wave
  const int c0s = (w * 18) >> 3, c0e = ((w + 1) * 18) >> 3;  // cell0: 18 chunks
  const int c1s = w * 4, c1e = c1s + 4;                      // cell1: 32 chunks

  float cc0[4] = {0.f, 0.f, 0.f, 0.f}, hh0[4] = {0.f, 0.f, 0.f, 0.f};
  float cc1[4] = {0.f, 0.f, 0.f, 0.f}, hh1[4] = {0.f, 0.f, 0.f, 0.f};

  for (unsigned p = 0; p < NPH; ++p) {
    const ushort* h0r = st + (size_t)(team * 2 + (p & 1)) * SSTRIDE;
    ushort* h0w       = st + (size_t)(team * 2 + ((p + 1) & 1)) * SSTRIDE;
    const ushort* h1r = st + (size_t)(16 + team * 2 + (p & 1)) * SSTRIDE;
    ushort* h1w       = st + (size_t)(16 + team * 2 + ((p + 1) & 1)) * SSTRIDE;
    const bool w0 = (p < T_);
    const int t1 = (int)p - 1;
    const bool w1 = (t1 >= 0 && t1 < T_);
    const int tc = (int)p - 2;
    const bool wc = (tc >= 0 && tc < T_);

    for (int i = tid; i < 64 * 17; i += 512) { z0[i] = 0.f; z1[i] = 0.f; }
    __syncthreads();

    if (w0) {
      // ---- cell0 GEMM slice: this wave's chunks of K=576 (2 x + 16 h0) ----
      f4 A0[4] = {}, A1[4] = {};
      for (int ch = c0s; ch < c0e; ++ch) {
        h8v af;
        if (ch < 2) {
          const float* xp = inputs + ((size_t)brow * T_ + p) * F_ + ch * 32 + khi * 8;
          const f4 a = *(const f4*)xp, b = *(const f4*)(xp + 4);
#pragma unroll
          for (int j = 0; j < 4; ++j) {
            af[j] = (_Float16)a[j]; af[4 + j] = (_Float16)b[j];
          }
        } else {
          af = ldA(h0r + ((ch - 2) * 64 + lane) * 8);
        }
#pragma unroll
        for (int ct = 0; ct < 4; ++ct) {
          const h8v whi = *(const h8v*)(wps + ((size_t)((ch * 4 + ct) * 2 + 0)) * 512 + lane * 8);
          const h8v wlo = *(const h8v*)(wps + ((size_t)((ch * 4 + ct) * 2 + 1)) * 512 + lane * 8);
          A0[ct] = __builtin_amdgcn_mfma_f32_16x16x32_f16(af, whi, A0[ct], 0, 0, 0);
          A1[ct] = __builtin_amdgcn_mfma_f32_16x16x32_f16(af, wlo, A1[ct], 0, 0, 0);
        }
      }
#pragma unroll
      for (int ct = 0; ct < 4; ++ct) {
        const f4 red = A0[ct] + A1[ct] * LO_SCALE;
#pragma unroll
        for (int j = 0; j < 4; ++j)
          atomicAdd(&z0[(ct * 16 + rlo) * 17 + rbase + j], red[j]);
      }
    }

    if (w1) {
      // ---- cell1 GEMM slice: this wave's 4 chunks of K=1024 ----
      f4 A0[4] = {}, A1[4] = {};
      for (int ch = c1s; ch < c1e; ++ch) {
        const ushort* Ab = (ch < 16) ? h0r : h1r;
        const h8v af = ldA(Ab + ((ch & 15) * 64 + lane) * 8);
#pragma unroll
        for (int ct = 0; ct < 4; ++ct) {
          const h8v whi = *(const h8v*)(wps + ((size_t)(144 + (ch * 4 + ct) * 2 + 0)) * 512 + lane * 8);
          const h8v wlo = *(const h8v*)(wps + ((size_t)(144 + (ch * 4 + ct) * 2 + 1)) * 512 + lane * 8);
          A0[ct] = __builtin_amdgcn_mfma_f32_16x16x32_f16(af, whi, A0[ct], 0, 0, 0);
          A1[ct] = __builtin_amdgcn_mfma_f32_16x16x32_f16(af, wlo, A1[ct], 0, 0, 0);
        }
      }
#pragma unroll
      for (int ct = 0; ct < 4; ++ct) {
        const f4 red = A0[ct] + A1[ct] * LO_SCALE;
#pragma unroll
        for (int j = 0; j < 4; ++j)
          atomicAdd(&z1[(ct * 16 + rlo) * 17 + rbase + j], red[j]);
      }
    }
    __syncthreads();

    // ---- elementwise updates: wave 0 = cell0, wave 1 = cell1 ----
    if (w == 0 && w0) {
      const float tt = timesT[p * B_ + brow];
      ushort vh[4];
#pragma unroll
      for (int i = 0; i < 4; ++i) {
        const int ul = khi * 4 + i, u = u0g + i;
        const float zi = z0[(ul * 4 + 0) * 17 + rlo] + b0v[u];
        const float zf = z0[(ul * 4 + 1) * 17 + rlo] + b0v[512 + u];
        const float zg = z0[(ul * 4 + 2) * 17 + rlo] + b0v[1024 + u];
        const float zo = z0[(ul * 4 + 3) * 17 + rlo] + b0v[1536 + u];
        const float ig = 1.f / (1.f + expf(-zi));
        const float fg = 1.f / (1.f + expf(-zf));
        const float gg = tanhf(zg);
        const float og = 1.f / (1.f + expf(-zo));
        const float c_t = fg * cc0[i] + ig * gg;
        const float h_t = og * tanhf(c_t);
        const float tau_u = tau0[u];
        float phi = fmodf(tt - s0v[u], tau_u);
        if (phi < 0.f) phi += tau_u;
        phi /= tau_u;
        float kt;
        if (phi < 0.5f * R_ON_) kt = phi * (2.0f / R_ON_);
        else if (phi < R_ON_)   kt = 2.0f - phi * (2.0f / R_ON_);
        else                    kt = ALPHA_ * phi;
        cc0[i] = kt * c_t + (1.0f - kt) * cc0[i];
        hh0[i] = kt * h_t + (1.0f - kt) * hh0[i];
        vh[i] = f2h(hh0[i]);
      }
      st_a64(h0w + faddr(rlo, u0g), pack4(vh));
    }
    if (w == 1 && w1) {
      const float tt = timesT[t1 * B_ + brow];
      ushort vh[4];
#pragma unroll
      for (int i = 0; i < 4; ++i) {
        const int ul = khi * 4 + i, u = u0g + i;
        const float zi = z1[(ul * 4 + 0) * 17 + rlo] + b1v[u];
        const float zf = z1[(ul * 4 + 1) * 17 + rlo] + b1v[512 + u];
        const float zg = z1[(ul * 4 + 2) * 17 + rlo] + b1v[1024 + u];
        const float zo = z1[(ul * 4 + 3) * 17 + rlo] + b1v[1536 + u];
        const float ig = 1.f / (1.f + expf(-zi));
        const float fg = 1.f / (1.f + expf(-zf));
        const float gg = tanhf(zg);
        const float og = 1.f / (1.f + expf(-zo));
        const float c_t = fg * cc1[i] + ig * gg;
        const float h_t = og * tanhf(c_t);
        const float tau_u = tau1[u];
        float phi = fmodf(tt - s1v[u], tau_u);
        if (phi < 0.f) phi += tau_u;
        phi /= tau_u;
        float kt;
        if (phi < 0.5f * R_ON_) kt = phi * (2.0f / R_ON_);
        else if (phi < R_ON_)   kt = 2.0f - phi * (2.0f / R_ON_);
        else                    kt = ALPHA_ * phi;
        cc1[i] = kt * c_t + (1.0f - kt) * cc1[i];
        hh1[i] = kt * h_t + (1.0f - kt) * hh1[i];
        vh[i] = f2h(hh1[i]);
      }
      st_a64(h1w + faddr(rlo, u0g), pack4(vh));
    }

    // ---- classifier: wave 2 of blocks s<16; row = team*16+s, t = p-2 ----
    if (w == 2 && wc && s < 16) {
      const int u = lane * 8;
      const int e = ((lane >> 2) * 64 + (s | ((lane & 3) << 4))) * 8;
      const u64 d0 = ld_a64(h1r + e);
      const u64 d1 = ld_a64(h1r + e + 4);
      float acc[NCLS_];
#pragma unroll
      for (int c = 0; c < NCLS_; ++c) acc[c] = 0.f;
#pragma unroll
      for (int j = 0; j < 8; ++j) {
        hu16 hb; hb.u = (ushort)(((j < 4) ? d0 : d1) >> (16 * (j & 3)));
        const float h = (float)hb.h;
        const float* wr = wfc + (size_t)(u + j) * NCLS_;
#pragma unroll
        for (int c = 0; c < NCLS_; ++c) acc[c] = fmaf(h, wr[c], acc[c]);
      }
#pragma unroll
      for (int off = 32; off >= 1; off >>= 1) {
#pragma unroll
        for (int c = 0; c < NCLS_; ++c) acc[c] += __shfl_xor(acc[c], off, 64);
      }
      if (lane == 0) {
        float lg[NCLS_];
        float m = -1e30f;
#pragma unroll
        for (int c = 0; c < NCLS_; ++c) { lg[c] = acc[c] + bfc[c]; m = fmaxf(m, lg[c]); }
        float sm = 0.f;
#pragma unroll
        for (int c = 0; c < NCLS_; ++c) { lg[c] = expf(lg[c] - m); sm += lg[c]; }
        const float inv = 1.0f / sm;
        float* op = out + ((size_t)(team * 16 + s) * T_ + tc) * NCLS_;
#pragma unroll
        for (int c = 0; c < NCLS_; ++c) op[c] = lg[c] * inv;
      }
    }

    // ---- per-TEAM barrier (32 blocks), RMW-free, monotonic flags ----
    if (p < NPH - 1) {
      asm volatile("s_waitcnt vmcnt(0)" ::: "memory");  // drain state stores
      __syncthreads();
      if (tid == 0)
        __hip_atomic_store(&bar[bid * 16], p + 1u, __ATOMIC_RELAXED, __HIP_MEMORY_SCOPE_AGENT);
      if (s == 0) {
        if (tid < SLICES) {
          while (__hip_atomic_load(&bar[(team * 32 + tid) * 16], __ATOMIC_RELAXED,
                                   __HIP_MEMORY_SCOPE_AGENT) < p + 1u)
            __builtin_amdgcn_s_sleep(2);
        }
        __syncthreads();
        if (tid == 0)
          __hip_atomic_store(&bar[4096 + team * 16], p + 1u, __ATOMIC_RELAXED,
                             __HIP_MEMORY_SCOPE_AGENT);
      } else {
        if (tid == 0) {
          while (__hip_atomic_load(&bar[4096 + team * 16], __ATOMIC_RELAXED,
                                   __HIP_MEMORY_SCOPE_AGENT) < p + 1u)
            __builtin_amdgcn_s_sleep(2);
        }
        __syncthreads();
      }
      asm volatile("" ::: "memory");
    }
  }
}

}  // namespace

extern "C" void kernel_launch(void* const* d_in, const int* in_sizes, int n_in,
                              void* d_out, int out_size, void* d_ws, size_t ws_size,
                              hipStream_t stream) {
  const float* inputs = (const float*)d_in[0];
  const float* times  = (const float*)d_in[1];
  const float* k0     = (const float*)d_in[2];
  const float* rk0    = (const float*)d_in[3];
  const float* b0     = (const float*)d_in[4];
  const float* tau0   = (const float*)d_in[5];
  const float* s0     = (const float*)d_in[6];
  const float* k1     = (const float*)d_in[7];
  const float* rk1    = (const float*)d_in[8];
  const float* b1     = (const float*)d_in[9];
  const float* tau1   = (const float*)d_in[10];
  const float* s1     = (const float*)d_in[11];
  const float* wfc    = (const float*)d_in[12];
  const float* bfc    = (const float*)d_in[13];
  float* out = (float*)d_out;

  // ws layout: wp[32*WSLICE ushort] | st[32*8192 ushort] | timesT[T*B f32] | bar[8192 u32]
  ushort* wp = (ushort*)d_ws;
  ushort* st = wp + (size_t)SLICES * WSLICE;
  float* timesT = (float*)(st + 32 * SSTRIDE);
  unsigned* bar = (unsigned*)(timesT + (size_t)T_ * B_);

  hipLaunchKernelGGL(init_kernel, dim3(2048), dim3(256), 0, stream,
                     wp, (unsigned*)st, timesT, bar, k0, rk0, k1, rk1, times);
  hipLaunchKernelGGL(plstm_kernel, dim3(NBLK), dim3(512), 0, stream,
                     inputs, b0, tau0, s0, b1, tau1, s1, wfc, bfc, out,
                     wp, st, timesT, bar);
}